// Round 1
// baseline (2818.194 us; speedup 1.0000x reference)
//
#include <hip/hip_runtime.h>
#include <hip/hip_bf16.h>

using bf16 = __hip_bfloat16;
typedef __bf16 bf16x8 __attribute__((ext_vector_type(8)));
typedef float f32x4 __attribute__((ext_vector_type(4)));
typedef short short4v __attribute__((ext_vector_type(4)));
typedef short short8v __attribute__((ext_vector_type(8)));

#define DEV __device__ __forceinline__

// B=32, S=64, T=64 (dec uses 63), V=32000, E=256, H=512, 4H=2048

DEV unsigned short f2bf(float f) {  // RNE float->bf16
  unsigned u = __builtin_bit_cast(unsigned, f);
  u = (u + 0x7fffu + ((u >> 16) & 1u)) >> 16;
  return (unsigned short)u;
}

DEV f32x4 mfma16(bf16x8 a, bf16x8 b, f32x4 c) {
  return __builtin_amdgcn_mfma_f32_16x16x32_bf16(a, b, c, 0, 0, 0);
}

// sense-reversing grid barrier; requires co-resident grid (cooperative launch)
DEV void grid_barrier(int* bar) {
  __syncthreads();
  if (threadIdx.x == 0) {
    __threadfence();  // make this block's global writes visible device-wide
    int g = __hip_atomic_load(bar + 1, __ATOMIC_RELAXED, __HIP_MEMORY_SCOPE_AGENT);
    int old = __hip_atomic_fetch_add(bar, 1, __ATOMIC_ACQ_REL, __HIP_MEMORY_SCOPE_AGENT);
    if (old == (int)gridDim.x - 1) {
      __hip_atomic_store(bar, 0, __ATOMIC_RELAXED, __HIP_MEMORY_SCOPE_AGENT);
      __hip_atomic_store(bar + 1, g + 1, __ATOMIC_RELEASE, __HIP_MEMORY_SCOPE_AGENT);
    } else {
      while (__hip_atomic_load(bar + 1, __ATOMIC_ACQUIRE, __HIP_MEMORY_SCOPE_AGENT) == g)
        __builtin_amdgcn_s_sleep(1);
    }
  }
  __syncthreads();
}

// ---------------- fp32 -> bf16 weight conversion (Whh for the 4 LSTM layers) ----
struct ConvJobs {
  const float* src[4];
  bf16* dst[4];
  int n[4];
  int cnt;
};

__global__ void convert_all(ConvJobs jobs) {
  long base = (long)blockIdx.x * blockDim.x + threadIdx.x;
  long stride = (long)gridDim.x * blockDim.x;
  for (int ji = 0; ji < jobs.cnt; ++ji) {
    const float* s = jobs.src[ji];
    bf16* d = jobs.dst[ji];
    long n4 = (long)jobs.n[ji] >> 2;
    for (long i = base; i < n4; i += stride) {
      f32x4 v = *(const f32x4*)(s + i * 4);
      short4v o;
#pragma unroll
      for (int j = 0; j < 4; ++j) o[j] = (short)f2bf(v[j]);
      *(short4v*)((short*)d + i * 4) = o;
    }
  }
}

// ---------------- embedding gather -> bf16 (E=256) ------------------------------
__global__ void embed_gather(const int* __restrict__ ids, const float* __restrict__ emb,
                             bf16* __restrict__ out, int rows, int tcols, int ids_stride) {
  long total = (long)rows * 64;  // 4 elems per item
  long stride = (long)gridDim.x * blockDim.x;
  for (long i = (long)blockIdx.x * blockDim.x + threadIdx.x; i < total; i += stride) {
    int row = (int)(i >> 6);
    int e = ((int)i & 63) * 4;
    int b = row / tcols;
    int t = row - b * tcols;
    int id = ids[b * ids_stride + t];
    f32x4 v = *(const f32x4*)(emb + (long)id * 256 + e);
    short4v o;
#pragma unroll
    for (int j = 0; j < 4; ++j) o[j] = (short)f2bf(v[j]);
    *(short4v*)((short*)out + (long)row * 256 + e) = o;
  }
}

// ---------------- zero out[:, 0, :] ---------------------------------------------
__global__ void zero_t0(float* __restrict__ out) {
  long total = 32l * 8000;  // float4 per item
  long stride = (long)gridDim.x * blockDim.x;
  f32x4 z{};
  for (long i = (long)blockIdx.x * blockDim.x + threadIdx.x; i < total; i += stride) {
    long b = i / 8000;
    long v = i - b * 8000;
    *(f32x4*)(out + b * 64 * 32000 + v * 4) = z;
  }
}

// ---------------- bf16 MFMA GEMM: C[M,N] = A[M,K] @ W[N,K]^T (+bias1+bias2) -----
// A bf16; W bf16 or fp32 (converted in staging). 128x128 tile, BK=64, 4 waves.
// affine_remap: C-row (b*63+t) written to out-row (b*64+t+1), N=32000.
__launch_bounds__(256)
__global__ void gemm_bf16(const bf16* __restrict__ A, const void* __restrict__ Wv, int b_fp32,
                          const float* __restrict__ bias1, const float* __restrict__ bias2,
                          float* __restrict__ C, int M, int N, int K, int affine_remap) {
  __shared__ __align__(16) bf16 As[128][64];
  __shared__ __align__(16) bf16 Bs[128][64];
  int nm = (M + 127) >> 7;
  int mt_blk = blockIdx.x % nm;   // m fastest -> concurrent blocks share W n-stripe in L2/LLC
  int nt_blk = blockIdx.x / nm;
  long m0 = (long)mt_blk * 128, n0 = (long)nt_blk * 128;
  int tid = threadIdx.x;
  int lane = tid & 63, wave = tid >> 6;
  int wm = wave & 1, wn = wave >> 1;
  int fl = lane & 15, fg = lane >> 4;
  const bf16* Wb = (const bf16*)Wv;
  const float* Wf = (const float*)Wv;
  f32x4 acc[4][4] = {};

  for (int k0 = 0; k0 < K; k0 += 64) {
    __syncthreads();
#pragma unroll
    for (int i = 0; i < 4; ++i) {
      int e = (i * 256 + tid) * 8;  // element index in 128x64 tile
      int row = e >> 6;
      int col = e & 63;
      long ar = m0 + row; if (ar >= M) ar = M - 1;
      *(bf16x8*)(&As[row][col]) = *(const bf16x8*)(A + ar * (long)K + k0 + col);
      long br = n0 + row; if (br >= N) br = N - 1;
      if (b_fp32) {
        const float* p = Wf + br * (long)K + k0 + col;
        f32x4 v0 = *(const f32x4*)p;
        f32x4 v1 = *(const f32x4*)(p + 4);
        short8v o;
#pragma unroll
        for (int j = 0; j < 4; ++j) { o[j] = (short)f2bf(v0[j]); o[j + 4] = (short)f2bf(v1[j]); }
        *(short8v*)(&Bs[row][col]) = o;
      } else {
        *(bf16x8*)(&Bs[row][col]) = *(const bf16x8*)(Wb + br * (long)K + k0 + col);
      }
    }
    __syncthreads();
#pragma unroll
    for (int kt = 0; kt < 2; ++kt) {
      bf16x8 af[4], bfr[4];
#pragma unroll
      for (int x = 0; x < 4; ++x)
        af[x] = *(const bf16x8*)(&As[wm * 64 + x * 16 + fl][kt * 32 + fg * 8]);
#pragma unroll
      for (int x = 0; x < 4; ++x)
        bfr[x] = *(const bf16x8*)(&Bs[wn * 64 + x * 16 + fl][kt * 32 + fg * 8]);
#pragma unroll
      for (int mi = 0; mi < 4; ++mi)
#pragma unroll
        for (int ni = 0; ni < 4; ++ni)
          acc[mi][ni] = mfma16(af[mi], bfr[ni], acc[mi][ni]);
    }
  }
  // epilogue: C/D layout col=lane&15, row=4*(lane>>4)+reg (guide-verified m89/m91)
#pragma unroll
  for (int mi = 0; mi < 4; ++mi) {
#pragma unroll
    for (int ni = 0; ni < 4; ++ni) {
#pragma unroll
      for (int r = 0; r < 4; ++r) {
        long row = m0 + wm * 64 + mi * 16 + fg * 4 + r;
        long col = n0 + wn * 64 + ni * 16 + fl;
        if (row < M && col < N) {
          float v = acc[mi][ni][r];
          if (bias1) v += bias1[col];
          if (bias2) v += bias2[col];
          long orow = row;
          if (affine_remap) {
            unsigned rr = (unsigned)row;
            unsigned bq = rr / 63u;
            orow = (long)bq * 64 + (rr - bq * 63u) + 1;
          }
          C[orow * (long)N + col] = v;
        }
      }
    }
  }
}

// ---------------- LSTM recurrence (one layer), cooperative, 64 blocks x 256 -----
// Block owns 8 hidden dims (32 gate rows). Weights live in registers as MFMA
// B-fragments (loaded once). h history stored bf16 (is the next MFMA A operand).
// c stays fp32 in registers. One grid barrier per timestep.
__launch_bounds__(256)
__global__ void lstm_layer(const float* __restrict__ xg,   // [B,T,2048] incl. biases
                           const bf16* __restrict__ Whh,   // [2048,512] bf16
                           bf16* __restrict__ h_hist,      // [B,T,512] out
                           const bf16* __restrict__ h_init,// row b at h_init + b*hinit_stride
                           long hinit_stride,
                           const float* __restrict__ c_init, // [B,512]
                           float* __restrict__ c_final,      // [B,512]
                           int T, int* bar) {
  __shared__ float part[4][32][33];  // [wave][batch][gate-col], padded
  int tid = threadIdx.x;
  int lane = tid & 63, wave = tid >> 6;
  int fl = lane & 15, fg = lane >> 4;
  int n0 = blockIdx.x * 8;           // hidden dims [n0, n0+8)
  int b_t = tid & 31, d_t = tid >> 5;  // (batch, dim) for reduce/activation

  // preload weight fragments: wave w covers k in [w*128, w*128+128)
  bf16x8 wf[2][4];
#pragma unroll
  for (int nt = 0; nt < 2; ++nt) {
    int j = nt * 16 + fl;                       // gate-col 0..31
    long row = (long)(j >> 3) * 512 + n0 + (j & 7);  // gate gi = j>>3, dim = j&7
#pragma unroll
    for (int kt = 0; kt < 4; ++kt) {
      int k = (wave * 4 + kt) * 32 + fg * 8;
      wf[nt][kt] = *(const bf16x8*)(Whh + row * 512 + k);
    }
  }
  float c = c_init[(long)b_t * 512 + n0 + d_t];

  for (int s = 0; s < T; ++s) {
    // prefetch xg (independent of h) to overlap with MFMA phase
    const float* xr = xg + ((long)b_t * T + s) * 2048 + n0 + d_t;
    float xv[4];
#pragma unroll
    for (int gi = 0; gi < 4; ++gi) xv[gi] = xr[(long)gi * 512];

    const bf16* hp;
    long hstr;
    if (s == 0) { hp = h_init; hstr = hinit_stride; }
    else { hp = h_hist + (long)(s - 1) * 512; hstr = (long)T * 512; }

    f32x4 acc[2][2] = {};
#pragma unroll
    for (int kt = 0; kt < 4; ++kt) {
      int k = (wave * 4 + kt) * 32 + fg * 8;
      bf16x8 a0 = *(const bf16x8*)(hp + (long)fl * hstr + k);
      bf16x8 a1 = *(const bf16x8*)(hp + (long)(fl + 16) * hstr + k);
      acc[0][0] = mfma16(a0, wf[0][kt], acc[0][0]);
      acc[0][1] = mfma16(a0, wf[1][kt], acc[0][1]);
      acc[1][0] = mfma16(a1, wf[0][kt], acc[1][0]);
      acc[1][1] = mfma16(a1, wf[1][kt], acc[1][1]);
    }
#pragma unroll
    for (int mt = 0; mt < 2; ++mt)
#pragma unroll
      for (int nt = 0; nt < 2; ++nt)
#pragma unroll
        for (int r = 0; r < 4; ++r)
          part[wave][mt * 16 + fg * 4 + r][nt * 16 + fl] = acc[mt][nt][r];
    __syncthreads();

    // reduce 4 K-partials + activations; thread (b_t, d_t)
    float g4[4];
#pragma unroll
    for (int gi = 0; gi < 4; ++gi) {
      int j = gi * 8 + d_t;
      g4[gi] = part[0][b_t][j] + part[1][b_t][j] + part[2][b_t][j] + part[3][b_t][j] + xv[gi];
    }
    float ig = 1.f / (1.f + __expf(-g4[0]));
    float fg_ = 1.f / (1.f + __expf(-g4[1]));
    float gg = tanhf(g4[2]);
    float og = 1.f / (1.f + __expf(-g4[3]));
    c = fg_ * c + ig * gg;
    float h = og * tanhf(c);
    ((unsigned short*)h_hist)[((long)b_t * T + s) * 512 + n0 + d_t] = f2bf(h);

    grid_barrier(bar);
  }
  c_final[(long)b_t * 512 + n0 + d_t] = c;
}

static void launch_lstm(const float* xg, const bf16* whh, bf16* hist, const bf16* hinit,
                        long hstride, const float* cinit, float* cfin, int T, int* bar,
                        hipStream_t stream) {
  void* args[9];
  args[0] = (void*)&xg;
  args[1] = (void*)&whh;
  args[2] = (void*)&hist;
  args[3] = (void*)&hinit;
  args[4] = (void*)&hstride;
  args[5] = (void*)&cinit;
  args[6] = (void*)&cfin;
  args[7] = (void*)&T;
  args[8] = (void*)&bar;
  hipLaunchCooperativeKernel((void*)lstm_layer, dim3(64), dim3(256), args, 0, stream);
}

extern "C" void kernel_launch(void* const* d_in, const int* in_sizes, int n_in,
                              void* d_out, int out_size, void* d_ws, size_t ws_size,
                              hipStream_t stream) {
  (void)in_sizes; (void)n_in; (void)out_size; (void)ws_size;
  const int*   source   = (const int*)d_in[0];
  const int*   target   = (const int*)d_in[1];
  const float* enc_emb  = (const float*)d_in[2];
  const float* enc_Wih0 = (const float*)d_in[3];
  const float* enc_Whh0 = (const float*)d_in[4];
  const float* enc_bih0 = (const float*)d_in[5];
  const float* enc_bhh0 = (const float*)d_in[6];
  const float* enc_Wih1 = (const float*)d_in[7];
  const float* enc_Whh1 = (const float*)d_in[8];
  const float* enc_bih1 = (const float*)d_in[9];
  const float* enc_bhh1 = (const float*)d_in[10];
  const float* dec_emb  = (const float*)d_in[11];
  const float* dec_Wih0 = (const float*)d_in[12];
  const float* dec_Whh0 = (const float*)d_in[13];
  const float* dec_bih0 = (const float*)d_in[14];
  const float* dec_bhh0 = (const float*)d_in[15];
  const float* dec_Wih1 = (const float*)d_in[16];
  const float* dec_Whh1 = (const float*)d_in[17];
  const float* dec_bih1 = (const float*)d_in[18];
  const float* dec_bhh1 = (const float*)d_in[19];
  const float* aff_W    = (const float*)d_in[20];
  const float* aff_b    = (const float*)d_in[21];
  float* out = (float*)d_out;

  // workspace layout (~34.2 MiB total)
  size_t off = 0;
  auto alc = [&](size_t bytes) {
    char* p = (char*)d_ws + off;
    off += (bytes + 255) & ~(size_t)255;
    return (void*)p;
  };
  int*   BAR = (int*)alc(256);
  bf16*  ZH  = (bf16*)alc(32 * 512 * 2);   // zero h_init (bf16)
  float* ZC  = (float*)alc(32 * 512 * 4);  // zero c_init (fp32)
  size_t zero_span = off;
  float* CE0 = (float*)alc(32 * 512 * 4);
  float* CE1 = (float*)alc(32 * 512 * 4);
  float* CD  = (float*)alc(32 * 512 * 4);
  bf16*  XE  = (bf16*)alc((size_t)2048 * 256 * 2);
  bf16*  XD  = (bf16*)alc((size_t)2016 * 256 * 2);
  bf16*  YE0 = (bf16*)alc((size_t)2048 * 512 * 2);
  bf16*  YE1 = (bf16*)alc((size_t)2048 * 512 * 2);
  bf16*  YD0 = (bf16*)alc((size_t)2016 * 512 * 2);
  bf16*  YD1 = (bf16*)alc((size_t)2016 * 512 * 2);
  float* XG  = (float*)alc((size_t)2048 * 2048 * 4);
  bf16*  WH0E = (bf16*)alc((size_t)2048 * 512 * 2);
  bf16*  WH1E = (bf16*)alc((size_t)2048 * 512 * 2);
  bf16*  WH0D = (bf16*)alc((size_t)2048 * 512 * 2);
  bf16*  WH1D = (bf16*)alc((size_t)2048 * 512 * 2);

  hipMemsetAsync(d_ws, 0, zero_span, stream);  // barrier state + zero inits

  ConvJobs cj;
  cj.src[0] = enc_Whh0; cj.dst[0] = WH0E; cj.n[0] = 2048 * 512;
  cj.src[1] = enc_Whh1; cj.dst[1] = WH1E; cj.n[1] = 2048 * 512;
  cj.src[2] = dec_Whh0; cj.dst[2] = WH0D; cj.n[2] = 2048 * 512;
  cj.src[3] = dec_Whh1; cj.dst[3] = WH1D; cj.n[3] = 2048 * 512;
  cj.cnt = 4;
  convert_all<<<dim3(1024), dim3(256), 0, stream>>>(cj);

  embed_gather<<<dim3(512), dim3(256), 0, stream>>>(source, enc_emb, XE, 2048, 64, 64);
  embed_gather<<<dim3(512), dim3(256), 0, stream>>>(target, dec_emb, XD, 2016, 63, 64);

  // encoder layer 0
  gemm_bf16<<<dim3(16 * 16), dim3(256), 0, stream>>>(XE, enc_Wih0, 1, enc_bih0, enc_bhh0,
                                                     XG, 2048, 2048, 256, 0);
  launch_lstm(XG, WH0E, YE0, ZH, 512, ZC, CE0, 64, BAR, stream);
  // encoder layer 1
  gemm_bf16<<<dim3(16 * 16), dim3(256), 0, stream>>>(YE0, enc_Wih1, 1, enc_bih1, enc_bhh1,
                                                     XG, 2048, 2048, 512, 0);
  launch_lstm(XG, WH1E, YE1, ZH, 512, ZC, CE1, 64, BAR, stream);
  // decoder layer 0 (init = encoder layer-0 finals)
  gemm_bf16<<<dim3(16 * 16), dim3(256), 0, stream>>>(XD, dec_Wih0, 1, dec_bih0, dec_bhh0,
                                                     XG, 2016, 2048, 256, 0);
  launch_lstm(XG, WH0D, YD0, YE0 + (size_t)63 * 512, 64 * 512, CE0, CD, 63, BAR, stream);
  // decoder layer 1 (init = encoder layer-1 finals)
  gemm_bf16<<<dim3(16 * 16), dim3(256), 0, stream>>>(YD0, dec_Wih1, 1, dec_bih1, dec_bhh1,
                                                     XG, 2016, 2048, 512, 0);
  launch_lstm(XG, WH1D, YD1, YE1 + (size_t)63 * 512, 64 * 512, CE1, CD, 63, BAR, stream);

  // output: out[:,0,:]=0, out[:,1:,:] = d1 @ aff_W.T + aff_b
  zero_t0<<<dim3(1000), dim3(256), 0, stream>>>(out);
  gemm_bf16<<<dim3(16 * 250), dim3(256), 0, stream>>>(YD1, aff_W, 1, aff_b, nullptr,
                                                      out, 2016, 32000, 512, 1);
}